// Round 4
// baseline (506.290 us; speedup 1.0000x reference)
//
#include <hip/hip_runtime.h>
#include <hip/hip_bf16.h>
#include <math.h>

#define Bn   8
#define Ln   4096
#define DINn 128
#define Hn   256
#define N2n  8
#define NLn  4

typedef __attribute__((ext_vector_type(4))) float f32x4;
typedef __attribute__((ext_vector_type(8))) short bf16x8;

__device__ __forceinline__ float gelu_f(float x) {
    float x2 = x * x;
    float inner = 0.7978845608028654f * x * fmaf(0.044715f, x2, 1.0f);
    float e = __expf(2.0f * inner);
    float th = 1.0f - 2.0f / (e + 1.0f);
    return 0.5f * x * (1.0f + th);
}

__device__ __forceinline__ float sigmoid_f(float x) {
    return 1.0f / (1.0f + __expf(-x));
}

__device__ __forceinline__ unsigned short f2bf(float f) {
    union { __hip_bfloat16 b; unsigned short u; } cv;
    cv.b = __float2bfloat16(f);
    return cv.u;
}

__device__ __forceinline__ uint4 pack8(float4 a, float4 b) {
    uint4 v;
    v.x = (unsigned)f2bf(a.x) | ((unsigned)f2bf(a.y) << 16);
    v.y = (unsigned)f2bf(a.z) | ((unsigned)f2bf(a.w) << 16);
    v.z = (unsigned)f2bf(b.x) | ((unsigned)f2bf(b.y) << 16);
    v.w = (unsigned)f2bf(b.z) | ((unsigned)f2bf(b.w) << 16);
    return v;
}

// ---------------------------------------------------------------------------
// S4D scan, one (b,h) row per BLOCK (256 threads, 4 waves), 16 elems/lane.
// Phase 1: state-only local scan. Phase 2: in-wave Kogge-Stone (mult w^16)
// building per-lane w^(16t) on the fly; cross-wave combine via LDS (3-term).
// Phase 3: re-run recurrence from corrected incoming state with projection,
// D-skip and gelu fused; bf16 out.
// ---------------------------------------------------------------------------
__global__ __launch_bounds__(256) void s4_scan_kernel(
    const float* __restrict__ hT,          // (B,H,L) f32
    unsigned short* __restrict__ yT,       // (B,H,L) bf16 out
    const float* __restrict__ log_dt,
    const float* __restrict__ log_A_real,
    const float* __restrict__ A_imag,
    const float* __restrict__ C_re,
    const float* __restrict__ C_im,
    const float* __restrict__ D_skip)
{
    __shared__ float u_lds[256 * 17];      // per-lane 16 elems, pitch 17 (odd)
    __shared__ float Ebuf[4][16];          // 4 wave-end states x 8 modes x (re,im)

    const int tid = threadIdx.x;
    const int w = tid >> 6;
    const int t = tid & 63;
    const int hh = blockIdx.x;
    const int b = blockIdx.y;

    const size_t rowbase = (size_t)(b * Hn + hh) * Ln + (size_t)tid * 16;
    const float* src = hT + rowbase;
    float* uL = &u_lds[tid * 17];

    #pragma unroll
    for (int j4 = 0; j4 < 4; ++j4) {
        float4 g = *(const float4*)(src + j4 * 4);
        uL[j4 * 4 + 0] = g.x; uL[j4 * 4 + 1] = g.y;
        uL[j4 * 4 + 2] = g.z; uL[j4 * 4 + 3] = g.w;
    }

    // ---- per-mode discretized pole w = exp(dt*A) ----
    const float dt = expf(log_dt[hh]);
    float wr[N2n], wi[N2n];
    #pragma unroll
    for (int n = 0; n < N2n; ++n) {
        float lar = log_A_real[hh * N2n + n];
        float aim = A_imag[hh * N2n + n];
        float are = -expf(lar);
        float mag = expf(are * dt);
        float s_, c_;
        sincosf(aim * dt, &s_, &c_);
        wr[n] = mag * c_; wi[n] = mag * s_;
    }

    // ---- phase 1: local state-only scan over 16 elems ----
    float sr[N2n], si[N2n];
    #pragma unroll
    for (int n = 0; n < N2n; ++n) { sr[n] = 0.0f; si[n] = 0.0f; }
    #pragma unroll
    for (int j = 0; j < 16; ++j) {
        float u = uL[j];
        #pragma unroll
        for (int n = 0; n < N2n; ++n) {
            float nr = fmaf(wr[n], sr[n], fmaf(-wi[n], si[n], u));
            float ni = fmaf(wi[n], sr[n], wr[n] * si[n]);
            sr[n] = nr; si[n] = ni;
        }
    }

    // ---- phase 2: wave Kogge-Stone with mult=w^16; build acc=w^(16t) ----
    float mr[N2n], mi[N2n], ar[N2n], ai[N2n];
    #pragma unroll
    for (int n = 0; n < N2n; ++n) {
        float br = wr[n], bi = wi[n];
        #pragma unroll
        for (int q = 0; q < 4; ++q) { float nr2 = br * br - bi * bi; bi = 2.0f * br * bi; br = nr2; }
        mr[n] = br; mi[n] = bi;    // w^16
        ar[n] = 1.0f; ai[n] = 0.0f;
    }
    #pragma unroll
    for (int dlt = 1; dlt < 64; dlt <<= 1) {
        #pragma unroll
        for (int n = 0; n < N2n; ++n) {
            float tr = __shfl_up(sr[n], (unsigned)dlt, 64);
            float ti = __shfl_up(si[n], (unsigned)dlt, 64);
            float trz = (t >= dlt) ? tr : 0.0f;
            float tiz = (t >= dlt) ? ti : 0.0f;
            sr[n] = fmaf(mr[n], trz, fmaf(-mi[n], tiz, sr[n]));
            si[n] = fmaf(mr[n], tiz, fmaf(mi[n], trz, si[n]));
            // acc *= mult if bit set (pre-squaring value = w^(16*dlt))
            float nar = ar[n] * mr[n] - ai[n] * mi[n];
            float nai = ar[n] * mi[n] + ai[n] * mr[n];
            bool bit = (t & dlt) != 0;
            ar[n] = bit ? nar : ar[n];
            ai[n] = bit ? nai : ai[n];
            // square mult
            float nr2 = mr[n] * mr[n] - mi[n] * mi[n];
            mi[n] = 2.0f * mr[n] * mi[n];
            mr[n] = nr2;
        }
    }
    // now mr/mi = w^1024 (M1024); ar/ai = w^(16t)

    // ---- cross-wave combine ----
    if (t == 63) {
        #pragma unroll
        for (int n = 0; n < N2n; ++n) {
            Ebuf[w][2 * n] = sr[n]; Ebuf[w][2 * n + 1] = si[n];
        }
    }
    __syncthreads();

    float prw[N2n], piw[N2n];
    #pragma unroll
    for (int n = 0; n < N2n; ++n) { prw[n] = 0.0f; piw[n] = 0.0f; }
    if (w >= 1) {
        #pragma unroll
        for (int n = 0; n < N2n; ++n) {
            prw[n] += Ebuf[w - 1][2 * n]; piw[n] += Ebuf[w - 1][2 * n + 1];
        }
    }
    if (w >= 2) {
        #pragma unroll
        for (int n = 0; n < N2n; ++n) {
            float er = Ebuf[w - 2][2 * n], ei = Ebuf[w - 2][2 * n + 1];
            prw[n] += mr[n] * er - mi[n] * ei;
            piw[n] += mr[n] * ei + mi[n] * er;
        }
    }
    if (w >= 3) {
        #pragma unroll
        for (int n = 0; n < N2n; ++n) {
            float m2r = mr[n] * mr[n] - mi[n] * mi[n];
            float m2i = 2.0f * mr[n] * mi[n];
            float er = Ebuf[w - 3][2 * n], ei = Ebuf[w - 3][2 * n + 1];
            prw[n] += m2r * er - m2i * ei;
            piw[n] += m2r * ei + m2i * er;
        }
    }

    // incoming state for this lane's chunk: X_t (exclusive) + w^(16t)*P_w
    #pragma unroll
    for (int n = 0; n < N2n; ++n) {
        float er = __shfl_up(sr[n], 1u, 64);
        float ei = __shfl_up(si[n], 1u, 64);
        float Xr = (t >= 1) ? er : 0.0f;
        float Xi = (t >= 1) ? ei : 0.0f;
        sr[n] = Xr + ar[n] * prw[n] - ai[n] * piw[n];
        si[n] = Xi + ar[n] * piw[n] + ai[n] * prw[n];
    }

    // ---- projection coefficients Ck = (C_re+iC_im)*(w-1)/A ----
    float cr[N2n], ci[N2n];
    #pragma unroll
    for (int n = 0; n < N2n; ++n) {
        float lar = log_A_real[hh * N2n + n];
        float aim = A_imag[hh * N2n + n];
        float are = -expf(lar);
        float nre = wr[n] - 1.0f, nim = wi[n];
        float inv = 1.0f / (are * are + aim * aim);
        float tre = (nre * are + nim * aim) * inv;
        float tim = (nim * are - nre * aim) * inv;
        float Cr = C_re[hh * N2n + n], Ci = C_im[hh * N2n + n];
        cr[n] = Cr * tre - Ci * tim;
        ci[n] = Cr * tim + Ci * tre;
    }
    const float Dsk = D_skip[hh];

    // ---- phase 3: re-run recurrence from corrected state + project ----
    unsigned short* dst = yT + rowbase;
    #pragma unroll
    for (int j8 = 0; j8 < 2; ++j8) {
        unsigned short rs[8];
        #pragma unroll
        for (int c = 0; c < 8; ++c) {
            float u = uL[j8 * 8 + c];
            float acc = 0.0f;
            #pragma unroll
            for (int n = 0; n < N2n; ++n) {
                float nr = fmaf(wr[n], sr[n], fmaf(-wi[n], si[n], u));
                float ni = fmaf(wi[n], sr[n], wr[n] * si[n]);
                sr[n] = nr; si[n] = ni;
                acc = fmaf(cr[n], nr, fmaf(-ci[n], ni, acc));
            }
            float yv = fmaf(2.0f, acc, Dsk * u);
            rs[c] = f2bf(gelu_f(yv));
        }
        uint4 o;
        o.x = (unsigned)rs[0] | ((unsigned)rs[1] << 16);
        o.y = (unsigned)rs[2] | ((unsigned)rs[3] << 16);
        o.z = (unsigned)rs[4] | ((unsigned)rs[5] << 16);
        o.w = (unsigned)rs[6] | ((unsigned)rs[7] << 16);
        *(uint4*)(dst + j8 * 8) = o;
    }
}

// ---------------------------------------------------------------------------
// t16: yT (b, 256, 4096) bf16 -> yN (b, 4096, 256) bf16.  64x64 LDS tile.
// ---------------------------------------------------------------------------
__global__ __launch_bounds__(256) void t16_kernel(
    const unsigned short* __restrict__ src, unsigned short* __restrict__ dst)
{
    __shared__ unsigned short tl[64 * 66];
    const int tid = threadIdx.x;
    const int l0 = blockIdx.x * 64, h0 = blockIdx.y * 64, b = blockIdx.z;
    #pragma unroll
    for (int it = 0; it < 2; ++it) {
        int idx = it * 256 + tid; int r = idx >> 3, c8 = idx & 7;
        uint4 g = *(const uint4*)(src + ((size_t)(b * Hn + h0 + r)) * Ln + l0 + c8 * 8);
        unsigned short* p = &tl[r * 66 + c8 * 8];
        p[0] = g.x & 0xffff; p[1] = g.x >> 16;
        p[2] = g.y & 0xffff; p[3] = g.y >> 16;
        p[4] = g.z & 0xffff; p[5] = g.z >> 16;
        p[6] = g.w & 0xffff; p[7] = g.w >> 16;
    }
    __syncthreads();
    #pragma unroll
    for (int it = 0; it < 2; ++it) {
        int idx = it * 256 + tid; int hc = idx & 7, lr = idx >> 3;
        unsigned short e[8];
        #pragma unroll
        for (int j = 0; j < 8; ++j) e[j] = tl[(hc * 8 + j) * 66 + lr];
        uint4 o;
        o.x = (unsigned)e[0] | ((unsigned)e[1] << 16);
        o.y = (unsigned)e[2] | ((unsigned)e[3] << 16);
        o.z = (unsigned)e[4] | ((unsigned)e[5] << 16);
        o.w = (unsigned)e[6] | ((unsigned)e[7] << 16);
        *(uint4*)(dst + ((size_t)(b * Ln + l0 + lr)) * Hn + h0 + hc * 8) = o;
    }
}

// ---------------------------------------------------------------------------
// MFMA GEMM: C(M,256) = A(M,KDIM) @ W^T (+bias,+GLU,+resid).
// 128x64 tile, BK=64, 4 waves, mfma_f32_16x16x32_bf16.
// WRT: also writes transposed HTout (B,256,L) via reused LDS tile.
// ---------------------------------------------------------------------------
template<int KDIM, bool GLU, bool ACVT, bool WRT>
__global__ __launch_bounds__(256) void mfma_gemm(
    const unsigned short* __restrict__ Abf,
    const float* __restrict__ Af,
    const float* __restrict__ W,
    const float* __restrict__ ba,
    const float* __restrict__ bg,
    const float* resid,              // aliases Hout (read-before-write, block-owned)
    float* Hout,                     // (M,256)
    float* HTout)                    // (B,256,L)
{
    constexpr int SM_MAIN = 128 * 72 * 2 + (GLU ? 2 : 1) * 64 * 72 * 2;
    constexpr int SM_TS = WRT ? (128 * 64 * 4) : 0;
    constexpr int SM = SM_MAIN > SM_TS ? SM_MAIN : SM_TS;
    __shared__ __align__(16) char smem[SM];
    unsigned short* As  = (unsigned short*)smem;
    unsigned short* Bs0 = As + 128 * 72;
    unsigned short* Bs1 = Bs0 + 64 * 72;   // GLU only
    float* ts = (float*)smem;              // reused after k-loop (WRT)

    const int tid = threadIdx.x;
    const int lane = tid & 63, w = tid >> 6;
    const int wm = w >> 1, wn = w & 1;
    const int lr = lane & 15, lq = lane >> 4;
    const int row0 = blockIdx.x * 128;
    const int n0 = blockIdx.y * 64;
    const int bb = row0 >> 12;
    const int l0 = row0 & (Ln - 1);

    f32x4 accA[4][2], accG[4][2];
    #pragma unroll
    for (int i = 0; i < 4; ++i)
        #pragma unroll
        for (int j = 0; j < 2; ++j) {
            accA[i][j] = (f32x4)0.0f;
            accG[i][j] = (f32x4)0.0f;
        }

    for (int kt = 0; kt < KDIM / 64; ++kt) {
        const int k0 = kt * 64;
        #pragma unroll
        for (int it = 0; it < 4; ++it) {
            int idx = it * 256 + tid; int m = idx >> 3, q = idx & 7;
            uint4 v;
            if constexpr (ACVT) {
                const float* s = Af + (size_t)(row0 + m) * KDIM + k0 + q * 8;
                float4 g1 = *(const float4*)s;
                float4 g2 = *(const float4*)(s + 4);
                v = pack8(g1, g2);
            } else {
                v = *(const uint4*)(Abf + (size_t)(row0 + m) * KDIM + k0 + q * 8);
            }
            *(uint4*)(&As[m * 72 + q * 8]) = v;
        }
        #pragma unroll
        for (int it = 0; it < 2; ++it) {
            int idx = it * 256 + tid; int p = idx >> 3, q = idx & 7;
            {
                const float* s = W + (size_t)(n0 + p) * KDIM + k0 + q * 8;
                float4 g1 = *(const float4*)s;
                float4 g2 = *(const float4*)(s + 4);
                *(uint4*)(&Bs0[p * 72 + q * 8]) = pack8(g1, g2);
            }
            if constexpr (GLU) {
                const float* s = W + (size_t)(256 + n0 + p) * KDIM + k0 + q * 8;
                float4 g1 = *(const float4*)s;
                float4 g2 = *(const float4*)(s + 4);
                *(uint4*)(&Bs1[p * 72 + q * 8]) = pack8(g1, g2);
            }
        }
        __syncthreads();
        #pragma unroll
        for (int kf = 0; kf < 2; ++kf) {
            bf16x8 av[4], bv[2], gv[2];
            #pragma unroll
            for (int mf = 0; mf < 4; ++mf)
                av[mf] = *(const bf16x8*)(&As[(wm * 64 + mf * 16 + lr) * 72 + (kf * 4 + lq) * 8]);
            #pragma unroll
            for (int nf = 0; nf < 2; ++nf) {
                bv[nf] = *(const bf16x8*)(&Bs0[(wn * 32 + nf * 16 + lr) * 72 + (kf * 4 + lq) * 8]);
                if constexpr (GLU)
                    gv[nf] = *(const bf16x8*)(&Bs1[(wn * 32 + nf * 16 + lr) * 72 + (kf * 4 + lq) * 8]);
            }
            #pragma unroll
            for (int mf = 0; mf < 4; ++mf)
                #pragma unroll
                for (int nf = 0; nf < 2; ++nf) {
                    accA[mf][nf] = __builtin_amdgcn_mfma_f32_16x16x32_bf16(av[mf], bv[nf], accA[mf][nf], 0, 0, 0);
                    if constexpr (GLU)
                        accG[mf][nf] = __builtin_amdgcn_mfma_f32_16x16x32_bf16(av[mf], gv[nf], accG[mf][nf], 0, 0, 0);
                }
        }
        __syncthreads();
    }

    // ---- epilogue ----
    int pc[2]; float bA[2], bG[2];
    #pragma unroll
    for (int nf = 0; nf < 2; ++nf) {
        pc[nf] = n0 + wn * 32 + nf * 16 + lr;
        bA[nf] = ba[pc[nf]];
        if constexpr (GLU) bG[nf] = bg[pc[nf]];
    }
    #pragma unroll
    for (int mf = 0; mf < 4; ++mf) {
        #pragma unroll
        for (int r = 0; r < 4; ++r) {
            int m_loc = wm * 64 + mf * 16 + lq * 4 + r;
            size_t rbase = (size_t)(row0 + m_loc) * Hn;
            #pragma unroll
            for (int nf = 0; nf < 2; ++nf) {
                float o;
                if constexpr (GLU) {
                    float aval = accA[mf][nf][r] + bA[nf];
                    float gval = accG[mf][nf][r] + bG[nf];
                    o = aval * sigmoid_f(gval) + resid[rbase + pc[nf]];
                } else {
                    o = accA[mf][nf][r] + bA[nf];
                }
                Hout[rbase + pc[nf]] = o;
                if constexpr (WRT)
                    ts[(wn * 32 + nf * 16 + lr) * 128 + m_loc] = o;
            }
        }
    }
    if constexpr (WRT) {
        __syncthreads();
        #pragma unroll
        for (int it = 0; it < 8; ++it) {
            int idx = it * 256 + tid;
            int nn = idx >> 5, m4 = (idx & 31) * 4;
            float4 o = *(const float4*)(&ts[nn * 128 + m4]);
            *(float4*)(HTout + (size_t)(bb * Hn + n0 + nn) * Ln + l0 + m4) = o;
        }
    }
}

extern "C" void kernel_launch(void* const* d_in, const int* in_sizes, int n_in,
                              void* d_out, int out_size, void* d_ws, size_t ws_size,
                              hipStream_t stream) {
    (void)in_sizes; (void)n_in; (void)out_size; (void)ws_size;
    const float* x          = (const float*)d_in[0];
    const float* enc_w      = (const float*)d_in[1];
    const float* enc_b      = (const float*)d_in[2];
    const float* log_dt     = (const float*)d_in[3];
    const float* log_A_real = (const float*)d_in[4];
    const float* A_imag     = (const float*)d_in[5];
    const float* C_re       = (const float*)d_in[6];
    const float* C_im       = (const float*)d_in[7];
    const float* D_skip     = (const float*)d_in[8];
    const float* out_w      = (const float*)d_in[9];
    const float* out_b      = (const float*)d_in[10];

    const size_t NE = (size_t)Bn * Hn * Ln;
    float* h  = (float*)d_out;                        // (B,L,H) residual stream
    float* hT = (float*)d_ws;                         // (B,H,L) f32
    unsigned short* yT = (unsigned short*)(hT + NE);  // (B,H,L) bf16
    unsigned short* yN = yT + NE;                     // (B,L,H) bf16

    const dim3 gb(256);

    // encoder: h,hT = x @ enc_w^T + enc_b
    mfma_gemm<DINn, false, true, true><<<dim3(256, 4), gb, 0, stream>>>(
        nullptr, x, enc_w, enc_b, nullptr, nullptr, h, hT);

    for (int i = 0; i < NLn; ++i) {
        s4_scan_kernel<<<dim3(Hn, Bn), gb, 0, stream>>>(
            hT, yT,
            log_dt + (size_t)i * Hn,
            log_A_real + (size_t)i * Hn * N2n,
            A_imag + (size_t)i * Hn * N2n,
            C_re + (size_t)i * Hn * N2n,
            C_im + (size_t)i * Hn * N2n,
            D_skip + (size_t)i * Hn);
        t16_kernel<<<dim3(64, 4, 8), gb, 0, stream>>>(yT, yN);
        const float* wlay = out_w + (size_t)i * 2 * Hn * Hn;
        const float* bl = out_b + (size_t)i * 2 * Hn;
        if (i == NLn - 1) {
            mfma_gemm<Hn, true, false, false><<<dim3(256, 4), gb, 0, stream>>>(
                yN, nullptr, wlay, bl, bl + Hn, h, h, nullptr);
        } else {
            mfma_gemm<Hn, true, false, true><<<dim3(256, 4), gb, 0, stream>>>(
                yN, nullptr, wlay, bl, bl + Hn, h, h, hT);
        }
    }
}

// Round 5
// 403.189 us; speedup vs baseline: 1.2557x; 1.2557x over previous
//
#include <hip/hip_runtime.h>
#include <hip/hip_bf16.h>
#include <math.h>

#define Bn   8
#define Ln   4096
#define DINn 128
#define Hn   256
#define N2n  8
#define NLn  4

typedef __attribute__((ext_vector_type(4))) float f32x4;
typedef __attribute__((ext_vector_type(8))) short bf16x8;

__device__ __forceinline__ float gelu_f(float x) {
    float x2 = x * x;
    float inner = 0.7978845608028654f * x * fmaf(0.044715f, x2, 1.0f);
    float e = __expf(2.0f * inner);
    float th = 1.0f - 2.0f / (e + 1.0f);
    return 0.5f * x * (1.0f + th);
}

__device__ __forceinline__ float sigmoid_f(float x) {
    return 1.0f / (1.0f + __expf(-x));
}

__device__ __forceinline__ unsigned short f2bf(float f) {
    union { __hip_bfloat16 b; unsigned short u; } cv;
    cv.b = __float2bfloat16(f);
    return cv.u;
}

__device__ __forceinline__ uint4 pack8(float4 a, float4 b) {
    uint4 v;
    v.x = (unsigned)f2bf(a.x) | ((unsigned)f2bf(a.y) << 16);
    v.y = (unsigned)f2bf(a.z) | ((unsigned)f2bf(a.w) << 16);
    v.z = (unsigned)f2bf(b.x) | ((unsigned)f2bf(b.y) << 16);
    v.w = (unsigned)f2bf(b.z) | ((unsigned)f2bf(b.w) << 16);
    return v;
}

// ---------------------------------------------------------------------------
// S4D scan: y = gelu(conv(u,K) + D*u), one (b,h) row per WAVE, 64 elems/lane,
// u held entirely in REGISTERS (no LDS -> no ds_read latency chain, no LDS
// occupancy cap).  grid (H/4, B), block 256 = 4 independent waves.
// Phase 1: local scan + projection (y overwrites u in regs).
// Phase 2: wave Kogge-Stone on chunk end-states, multiplier w^64.
// Phase 3: per-elem correction 2*Re(Ck w^(j+1) p), gelu, bf16 store.
// ---------------------------------------------------------------------------
__global__ __launch_bounds__(256) void s4_scan_kernel(
    const float* __restrict__ hT,          // (B,H,L) f32
    unsigned short* __restrict__ yT,       // (B,H,L) bf16 out
    const float* __restrict__ log_dt,
    const float* __restrict__ log_A_real,
    const float* __restrict__ A_imag,
    const float* __restrict__ C_re,
    const float* __restrict__ C_im,
    const float* __restrict__ D_skip)
{
    const int tid = threadIdx.x;
    const int v = tid >> 6;
    const int t = tid & 63;
    const int h = blockIdx.x * 4 + v;
    const int b = blockIdx.y;

    const size_t rowbase = (size_t)(b * Hn + h) * Ln + (size_t)t * 64;
    const float* src = hT + rowbase;

    float u[64];
    #pragma unroll
    for (int j4 = 0; j4 < 16; ++j4) {
        float4 g = *(const float4*)(src + j4 * 4);
        u[j4 * 4 + 0] = g.x; u[j4 * 4 + 1] = g.y;
        u[j4 * 4 + 2] = g.z; u[j4 * 4 + 3] = g.w;
    }

    // per-mode params (wave-uniform; computed redundantly per lane)
    float dt = expf(log_dt[h]);
    float wr[N2n], wi[N2n], cr[N2n], ci[N2n];
    #pragma unroll
    for (int n = 0; n < N2n; ++n) {
        float lar = log_A_real[h * N2n + n];
        float aim = A_imag[h * N2n + n];
        float are = -expf(lar);
        float dre = are * dt, dimv = aim * dt;
        float mag = expf(dre);
        float s_, c_;
        sincosf(dimv, &s_, &c_);
        float w_re = mag * c_, w_im = mag * s_;
        wr[n] = w_re; wi[n] = w_im;
        // Ck = (C_re + i C_im) * (w - 1) / A,  A = are + i*aim
        float nre = w_re - 1.0f, nim = w_im;
        float inv = 1.0f / (are * are + aim * aim);
        float tre = (nre * are + nim * aim) * inv;
        float tim = (nim * are - nre * aim) * inv;
        float Cr = C_re[h * N2n + n], Ci = C_im[h * N2n + n];
        cr[n] = Cr * tre - Ci * tim;
        ci[n] = Cr * tim + Ci * tre;
    }
    const float Dsk = D_skip[h];

    // ---- phase 1: local scan (zero init); y_loc + D*u overwrites u (regs) ----
    float sr[N2n], si[N2n];
    #pragma unroll
    for (int n = 0; n < N2n; ++n) { sr[n] = 0.0f; si[n] = 0.0f; }
    #pragma unroll
    for (int j = 0; j < 64; ++j) {
        float uu = u[j];
        float acc = 0.0f;
        #pragma unroll
        for (int n = 0; n < N2n; ++n) {
            float nr = fmaf(wr[n], sr[n], fmaf(-wi[n], si[n], uu));
            float ni = fmaf(wi[n], sr[n], wr[n] * si[n]);
            sr[n] = nr; si[n] = ni;
            acc = fmaf(cr[n], nr, fmaf(-ci[n], ni, acc));
        }
        u[j] = fmaf(2.0f, acc, Dsk * uu);
    }

    // ---- phase 2: inclusive wave scan of end-states, multiplier w^64 ----
    float mr[N2n], mi[N2n];
    #pragma unroll
    for (int n = 0; n < N2n; ++n) {
        float ar = wr[n], ai = wi[n];
        #pragma unroll
        for (int q = 0; q < 6; ++q) { float nr2 = ar * ar - ai * ai; ai = 2.0f * ar * ai; ar = nr2; }
        mr[n] = ar; mi[n] = ai;   // w^64
    }
    #pragma unroll
    for (int dlt = 1; dlt < 64; dlt <<= 1) {
        #pragma unroll
        for (int n = 0; n < N2n; ++n) {
            float tr = __shfl_up(sr[n], (unsigned)dlt, 64);
            float ti = __shfl_up(si[n], (unsigned)dlt, 64);
            float trz = (t >= dlt) ? tr : 0.0f;
            float tiz = (t >= dlt) ? ti : 0.0f;
            sr[n] = fmaf(mr[n], trz, fmaf(-mi[n], tiz, sr[n]));
            si[n] = fmaf(mr[n], tiz, fmaf(mi[n], trz, si[n]));
        }
        #pragma unroll
        for (int n = 0; n < N2n; ++n) {
            float nr2 = mr[n] * mr[n] - mi[n] * mi[n];
            mi[n] = 2.0f * mr[n] * mi[n];
            mr[n] = nr2;
        }
    }
    // exclusive prefix = incoming state for this lane's chunk
    float pr[N2n], pim[N2n];
    #pragma unroll
    for (int n = 0; n < N2n; ++n) {
        float er = __shfl_up(sr[n], 1u, 64);
        float ei = __shfl_up(si[n], 1u, 64);
        pr[n]  = (t >= 1) ? er : 0.0f;
        pim[n] = (t >= 1) ? ei : 0.0f;
    }

    // ---- phase 3: add correction 2*Re(Ck * w^(j+1) * p), gelu, store ----
    float dr2[N2n], di2[N2n];
    #pragma unroll
    for (int n = 0; n < N2n; ++n) { dr2[n] = cr[n]; di2[n] = ci[n]; }
    unsigned short* dst = yT + rowbase;
    #pragma unroll
    for (int j8 = 0; j8 < 8; ++j8) {
        unsigned short rs[8];
        #pragma unroll
        for (int c = 0; c < 8; ++c) {
            float corr = 0.0f;
            #pragma unroll
            for (int n = 0; n < N2n; ++n) {
                float nr2 = dr2[n] * wr[n] - di2[n] * wi[n];
                float ni2 = dr2[n] * wi[n] + di2[n] * wr[n];
                dr2[n] = nr2; di2[n] = ni2;
                corr = fmaf(nr2, pr[n], fmaf(-ni2, pim[n], corr));
            }
            float yv = fmaf(2.0f, corr, u[j8 * 8 + c]);
            rs[c] = f2bf(gelu_f(yv));
        }
        uint4 o;
        o.x = (unsigned)rs[0] | ((unsigned)rs[1] << 16);
        o.y = (unsigned)rs[2] | ((unsigned)rs[3] << 16);
        o.z = (unsigned)rs[4] | ((unsigned)rs[5] << 16);
        o.w = (unsigned)rs[6] | ((unsigned)rs[7] << 16);
        *(uint4*)(dst + j8 * 8) = o;
    }
}

// ---------------------------------------------------------------------------
// t16: yT (b, 256, 4096) bf16 -> yN (b, 4096, 256) bf16.  64x64 LDS tile.
// ---------------------------------------------------------------------------
__global__ __launch_bounds__(256) void t16_kernel(
    const unsigned short* __restrict__ src, unsigned short* __restrict__ dst)
{
    __shared__ unsigned short tl[64 * 66];
    const int tid = threadIdx.x;
    const int l0 = blockIdx.x * 64, h0 = blockIdx.y * 64, b = blockIdx.z;
    #pragma unroll
    for (int it = 0; it < 2; ++it) {
        int idx = it * 256 + tid; int r = idx >> 3, c8 = idx & 7;
        uint4 g = *(const uint4*)(src + ((size_t)(b * Hn + h0 + r)) * Ln + l0 + c8 * 8);
        unsigned short* p = &tl[r * 66 + c8 * 8];
        p[0] = g.x & 0xffff; p[1] = g.x >> 16;
        p[2] = g.y & 0xffff; p[3] = g.y >> 16;
        p[4] = g.z & 0xffff; p[5] = g.z >> 16;
        p[6] = g.w & 0xffff; p[7] = g.w >> 16;
    }
    __syncthreads();
    #pragma unroll
    for (int it = 0; it < 2; ++it) {
        int idx = it * 256 + tid; int hc = idx & 7, lr = idx >> 3;
        unsigned short e[8];
        #pragma unroll
        for (int j = 0; j < 8; ++j) e[j] = tl[(hc * 8 + j) * 66 + lr];
        uint4 o;
        o.x = (unsigned)e[0] | ((unsigned)e[1] << 16);
        o.y = (unsigned)e[2] | ((unsigned)e[3] << 16);
        o.z = (unsigned)e[4] | ((unsigned)e[5] << 16);
        o.w = (unsigned)e[6] | ((unsigned)e[7] << 16);
        *(uint4*)(dst + ((size_t)(b * Ln + l0 + lr)) * Hn + h0 + hc * 8) = o;
    }
}

// ---------------------------------------------------------------------------
// MFMA GEMM: C(M,256) = A(M,KDIM) @ W^T (+bias,+GLU,+resid).
// 128x64 tile, BK=64, 4 waves, mfma_f32_16x16x32_bf16.
// WRT: also writes transposed HTout (B,256,L) via reused LDS tile.
// ---------------------------------------------------------------------------
template<int KDIM, bool GLU, bool ACVT, bool WRT>
__global__ __launch_bounds__(256) void mfma_gemm(
    const unsigned short* __restrict__ Abf,
    const float* __restrict__ Af,
    const float* __restrict__ W,
    const float* __restrict__ ba,
    const float* __restrict__ bg,
    const float* resid,              // aliases Hout (read-before-write, block-owned)
    float* Hout,                     // (M,256)
    float* HTout)                    // (B,256,L)
{
    constexpr int SM_MAIN = 128 * 72 * 2 + (GLU ? 2 : 1) * 64 * 72 * 2;
    constexpr int SM_TS = WRT ? (128 * 64 * 4) : 0;
    constexpr int SM = SM_MAIN > SM_TS ? SM_MAIN : SM_TS;
    __shared__ __align__(16) char smem[SM];
    unsigned short* As  = (unsigned short*)smem;
    unsigned short* Bs0 = As + 128 * 72;
    unsigned short* Bs1 = Bs0 + 64 * 72;   // GLU only
    float* ts = (float*)smem;              // reused after k-loop (WRT)

    const int tid = threadIdx.x;
    const int lane = tid & 63, w = tid >> 6;
    const int wm = w >> 1, wn = w & 1;
    const int lr = lane & 15, lq = lane >> 4;
    const int row0 = blockIdx.x * 128;
    const int n0 = blockIdx.y * 64;
    const int bb = row0 >> 12;
    const int l0 = row0 & (Ln - 1);

    f32x4 accA[4][2], accG[4][2];
    #pragma unroll
    for (int i = 0; i < 4; ++i)
        #pragma unroll
        for (int j = 0; j < 2; ++j) {
            accA[i][j] = (f32x4)0.0f;
            accG[i][j] = (f32x4)0.0f;
        }

    for (int kt = 0; kt < KDIM / 64; ++kt) {
        const int k0 = kt * 64;
        #pragma unroll
        for (int it = 0; it < 4; ++it) {
            int idx = it * 256 + tid; int m = idx >> 3, q = idx & 7;
            uint4 v;
            if constexpr (ACVT) {
                const float* s = Af + (size_t)(row0 + m) * KDIM + k0 + q * 8;
                float4 g1 = *(const float4*)s;
                float4 g2 = *(const float4*)(s + 4);
                v = pack8(g1, g2);
            } else {
                v = *(const uint4*)(Abf + (size_t)(row0 + m) * KDIM + k0 + q * 8);
            }
            *(uint4*)(&As[m * 72 + q * 8]) = v;
        }
        #pragma unroll
        for (int it = 0; it < 2; ++it) {
            int idx = it * 256 + tid; int p = idx >> 3, q = idx & 7;
            {
                const float* s = W + (size_t)(n0 + p) * KDIM + k0 + q * 8;
                float4 g1 = *(const float4*)s;
                float4 g2 = *(const float4*)(s + 4);
                *(uint4*)(&Bs0[p * 72 + q * 8]) = pack8(g1, g2);
            }
            if constexpr (GLU) {
                const float* s = W + (size_t)(256 + n0 + p) * KDIM + k0 + q * 8;
                float4 g1 = *(const float4*)s;
                float4 g2 = *(const float4*)(s + 4);
                *(uint4*)(&Bs1[p * 72 + q * 8]) = pack8(g1, g2);
            }
        }
        __syncthreads();
        #pragma unroll
        for (int kf = 0; kf < 2; ++kf) {
            bf16x8 av[4], bv[2], gv[2];
            #pragma unroll
            for (int mf = 0; mf < 4; ++mf)
                av[mf] = *(const bf16x8*)(&As[(wm * 64 + mf * 16 + lr) * 72 + (kf * 4 + lq) * 8]);
            #pragma unroll
            for (int nf = 0; nf < 2; ++nf) {
                bv[nf] = *(const bf16x8*)(&Bs0[(wn * 32 + nf * 16 + lr) * 72 + (kf * 4 + lq) * 8]);
                if constexpr (GLU)
                    gv[nf] = *(const bf16x8*)(&Bs1[(wn * 32 + nf * 16 + lr) * 72 + (kf * 4 + lq) * 8]);
            }
            #pragma unroll
            for (int mf = 0; mf < 4; ++mf)
                #pragma unroll
                for (int nf = 0; nf < 2; ++nf) {
                    accA[mf][nf] = __builtin_amdgcn_mfma_f32_16x16x32_bf16(av[mf], bv[nf], accA[mf][nf], 0, 0, 0);
                    if constexpr (GLU)
                        accG[mf][nf] = __builtin_amdgcn_mfma_f32_16x16x32_bf16(av[mf], gv[nf], accG[mf][nf], 0, 0, 0);
                }
        }
        __syncthreads();
    }

    // ---- epilogue ----
    int pc[2]; float bA[2], bG[2];
    #pragma unroll
    for (int nf = 0; nf < 2; ++nf) {
        pc[nf] = n0 + wn * 32 + nf * 16 + lr;
        bA[nf] = ba[pc[nf]];
        if constexpr (GLU) bG[nf] = bg[pc[nf]];
    }
    #pragma unroll
    for (int mf = 0; mf < 4; ++mf) {
        #pragma unroll
        for (int r = 0; r < 4; ++r) {
            int m_loc = wm * 64 + mf * 16 + lq * 4 + r;
            size_t rbase = (size_t)(row0 + m_loc) * Hn;
            #pragma unroll
            for (int nf = 0; nf < 2; ++nf) {
                float o;
                if constexpr (GLU) {
                    float aval = accA[mf][nf][r] + bA[nf];
                    float gval = accG[mf][nf][r] + bG[nf];
                    o = aval * sigmoid_f(gval) + resid[rbase + pc[nf]];
                } else {
                    o = accA[mf][nf][r] + bA[nf];
                }
                Hout[rbase + pc[nf]] = o;
                if constexpr (WRT)
                    ts[(wn * 32 + nf * 16 + lr) * 128 + m_loc] = o;
            }
        }
    }
    if constexpr (WRT) {
        __syncthreads();
        #pragma unroll
        for (int it = 0; it < 8; ++it) {
            int idx = it * 256 + tid;
            int nn = idx >> 5, m4 = (idx & 31) * 4;
            float4 o = *(const float4*)(&ts[nn * 128 + m4]);
            *(float4*)(HTout + (size_t)(bb * Hn + n0 + nn) * Ln + l0 + m4) = o;
        }
    }
}

extern "C" void kernel_launch(void* const* d_in, const int* in_sizes, int n_in,
                              void* d_out, int out_size, void* d_ws, size_t ws_size,
                              hipStream_t stream) {
    (void)in_sizes; (void)n_in; (void)out_size; (void)ws_size;
    const float* x          = (const float*)d_in[0];
    const float* enc_w      = (const float*)d_in[1];
    const float* enc_b      = (const float*)d_in[2];
    const float* log_dt     = (const float*)d_in[3];
    const float* log_A_real = (const float*)d_in[4];
    const float* A_imag     = (const float*)d_in[5];
    const float* C_re       = (const float*)d_in[6];
    const float* C_im       = (const float*)d_in[7];
    const float* D_skip     = (const float*)d_in[8];
    const float* out_w      = (const float*)d_in[9];
    const float* out_b      = (const float*)d_in[10];

    const size_t NE = (size_t)Bn * Hn * Ln;
    float* h  = (float*)d_out;                        // (B,L,H) residual stream
    float* hT = (float*)d_ws;                         // (B,H,L) f32
    unsigned short* yT = (unsigned short*)(hT + NE);  // (B,H,L) bf16
    unsigned short* yN = yT + NE;                     // (B,L,H) bf16

    const dim3 gb(256);

    // encoder: h,hT = x @ enc_w^T + enc_b
    mfma_gemm<DINn, false, true, true><<<dim3(256, 4), gb, 0, stream>>>(
        nullptr, x, enc_w, enc_b, nullptr, nullptr, h, hT);

    for (int i = 0; i < NLn; ++i) {
        s4_scan_kernel<<<dim3(Hn / 4, Bn), gb, 0, stream>>>(
            hT, yT,
            log_dt + (size_t)i * Hn,
            log_A_real + (size_t)i * Hn * N2n,
            A_imag + (size_t)i * Hn * N2n,
            C_re + (size_t)i * Hn * N2n,
            C_im + (size_t)i * Hn * N2n,
            D_skip + (size_t)i * Hn);
        t16_kernel<<<dim3(64, 4, 8), gb, 0, stream>>>(yT, yN);
        const float* wlay = out_w + (size_t)i * 2 * Hn * Hn;
        const float* bl = out_b + (size_t)i * 2 * Hn;
        if (i == NLn - 1) {
            mfma_gemm<Hn, true, false, false><<<dim3(256, 4), gb, 0, stream>>>(
                yN, nullptr, wlay, bl, bl + Hn, h, h, nullptr);
        } else {
            mfma_gemm<Hn, true, false, true><<<dim3(256, 4), gb, 0, stream>>>(
                yN, nullptr, wlay, bl, bl + Hn, h, h, hT);
        }
    }
}

// Round 10
// 349.283 us; speedup vs baseline: 1.4495x; 1.1543x over previous
//
#include <hip/hip_runtime.h>
#include <hip/hip_bf16.h>
#include <math.h>

#define Bn   8
#define Ln   4096
#define DINn 128
#define Hn   256
#define N2n  8
#define NLn  4

typedef __attribute__((ext_vector_type(4))) float f32x4;
typedef __attribute__((ext_vector_type(8))) short bf16x8;

__device__ __forceinline__ float gelu_f(float x) {
    float x2 = x * x;
    float inner = 0.7978845608028654f * x * fmaf(0.044715f, x2, 1.0f);
    float e = __expf(2.0f * inner);
    float th = 1.0f - 2.0f / (e + 1.0f);
    return 0.5f * x * (1.0f + th);
}

__device__ __forceinline__ float sigmoid_f(float x) {
    return 1.0f / (1.0f + __expf(-x));
}

__device__ __forceinline__ unsigned short f2bf(float f) {
    union { __hip_bfloat16 b; unsigned short u; } cv;
    cv.b = __float2bfloat16(f);
    return cv.u;
}

__device__ __forceinline__ uint4 pack8(float4 a, float4 b) {
    uint4 v;
    v.x = (unsigned)f2bf(a.x) | ((unsigned)f2bf(a.y) << 16);
    v.y = (unsigned)f2bf(a.z) | ((unsigned)f2bf(a.w) << 16);
    v.z = (unsigned)f2bf(b.x) | ((unsigned)f2bf(b.y) << 16);
    v.w = (unsigned)f2bf(b.z) | ((unsigned)f2bf(b.w) << 16);
    return v;
}

// ---------------------------------------------------------------------------
// S4D scan (round-3 proven version, verbatim): y = gelu(conv(u,K) + D*u),
// one (b,h) row per WAVE via LDS-staged u, 64 elems/lane.
// Phase 1: local scan + projection (overwrites u in LDS).
// Phase 2: wave Kogge-Stone on end-states, multiplier w^64.
// Phase 3: per-elem correction 2*Re(Ck w^(j+1) p), gelu, bf16 store.
// grid (H/4, B), block 256 = 4 independent waves.
// ---------------------------------------------------------------------------
__global__ __launch_bounds__(256) void s4_scan_kernel(
    const float* __restrict__ hT,          // (B,H,L) f32
    unsigned short* __restrict__ yT,       // (B,H,L) bf16 out
    const float* __restrict__ log_dt,
    const float* __restrict__ log_A_real,
    const float* __restrict__ A_imag,
    const float* __restrict__ C_re,
    const float* __restrict__ C_im,
    const float* __restrict__ D_skip)
{
    __shared__ float u_lds[4][64][65];
    const int tid = threadIdx.x;
    const int v = tid >> 6;
    const int t = tid & 63;
    const int h = blockIdx.x * 4 + v;
    const int b = blockIdx.y;

    const size_t rowbase = (size_t)(b * Hn + h) * Ln + (size_t)t * 64;
    const float* src = hT + rowbase;
    float* uL = &u_lds[v][t][0];

    #pragma unroll
    for (int j4 = 0; j4 < 16; ++j4) {
        float4 g = *(const float4*)(src + j4 * 4);
        uL[j4 * 4 + 0] = g.x; uL[j4 * 4 + 1] = g.y;
        uL[j4 * 4 + 2] = g.z; uL[j4 * 4 + 3] = g.w;
    }

    float dt = expf(log_dt[h]);
    float wr[N2n], wi[N2n], cr[N2n], ci[N2n];
    #pragma unroll
    for (int n = 0; n < N2n; ++n) {
        float lar = log_A_real[h * N2n + n];
        float aim = A_imag[h * N2n + n];
        float are = -expf(lar);
        float dre = are * dt, dimv = aim * dt;
        float mag = expf(dre);
        float s_, c_;
        sincosf(dimv, &s_, &c_);
        float w_re = mag * c_, w_im = mag * s_;
        wr[n] = w_re; wi[n] = w_im;
        float nre = w_re - 1.0f, nim = w_im;
        float inv = 1.0f / (are * are + aim * aim);
        float tre = (nre * are + nim * aim) * inv;
        float tim = (nim * are - nre * aim) * inv;
        float Cr = C_re[h * N2n + n], Ci = C_im[h * N2n + n];
        cr[n] = Cr * tre - Ci * tim;
        ci[n] = Cr * tim + Ci * tre;
    }
    const float Dsk = D_skip[h];

    // ---- phase 1: local scan (zero init); y_loc + D*u overwrites u in LDS ----
    float sr[N2n], si[N2n];
    #pragma unroll
    for (int n = 0; n < N2n; ++n) { sr[n] = 0.0f; si[n] = 0.0f; }
    #pragma unroll 4
    for (int j = 0; j < 64; ++j) {
        float u = uL[j];
        float acc = 0.0f;
        #pragma unroll
        for (int n = 0; n < N2n; ++n) {
            float nr = fmaf(wr[n], sr[n], fmaf(-wi[n], si[n], u));
            float ni = fmaf(wi[n], sr[n], wr[n] * si[n]);
            sr[n] = nr; si[n] = ni;
            acc = fmaf(cr[n], nr, fmaf(-ci[n], ni, acc));
        }
        uL[j] = fmaf(2.0f, acc, Dsk * u);
    }

    // ---- phase 2: inclusive wave scan of end-states, multiplier w^64 ----
    float mr[N2n], mi[N2n];
    #pragma unroll
    for (int n = 0; n < N2n; ++n) {
        float ar = wr[n], ai = wi[n];
        #pragma unroll
        for (int q = 0; q < 6; ++q) { float nr2 = ar * ar - ai * ai; ai = 2.0f * ar * ai; ar = nr2; }
        mr[n] = ar; mi[n] = ai;   // w^64
    }
    for (int dlt = 1; dlt < 64; dlt <<= 1) {
        #pragma unroll
        for (int n = 0; n < N2n; ++n) {
            float tr = __shfl_up(sr[n], (unsigned)dlt, 64);
            float ti = __shfl_up(si[n], (unsigned)dlt, 64);
            float trz = (t >= dlt) ? tr : 0.0f;
            float tiz = (t >= dlt) ? ti : 0.0f;
            sr[n] = fmaf(mr[n], trz, fmaf(-mi[n], tiz, sr[n]));
            si[n] = fmaf(mr[n], tiz, fmaf(mi[n], trz, si[n]));
        }
        #pragma unroll
        for (int n = 0; n < N2n; ++n) {
            float nr2 = mr[n] * mr[n] - mi[n] * mi[n];
            mi[n] = 2.0f * mr[n] * mi[n];
            mr[n] = nr2;
        }
    }
    float pr[N2n], pim[N2n];
    #pragma unroll
    for (int n = 0; n < N2n; ++n) {
        float er = __shfl_up(sr[n], 1u, 64);
        float ei = __shfl_up(si[n], 1u, 64);
        pr[n]  = (t >= 1) ? er : 0.0f;
        pim[n] = (t >= 1) ? ei : 0.0f;
    }

    // ---- phase 3: add correction 2*Re(Ck * w^(j+1) * p), gelu, store bf16 ----
    float dr2[N2n], di2[N2n];
    #pragma unroll
    for (int n = 0; n < N2n; ++n) { dr2[n] = cr[n]; di2[n] = ci[n]; }
    unsigned short* dst = yT + rowbase;
    for (int j8 = 0; j8 < 8; ++j8) {
        unsigned short rs[8];
        #pragma unroll
        for (int c = 0; c < 8; ++c) {
            float corr = 0.0f;
            #pragma unroll
            for (int n = 0; n < N2n; ++n) {
                float nr2 = dr2[n] * wr[n] - di2[n] * wi[n];
                float ni2 = dr2[n] * wi[n] + di2[n] * wr[n];
                dr2[n] = nr2; di2[n] = ni2;
                corr = fmaf(nr2, pr[n], fmaf(-ni2, pim[n], corr));
            }
            float yv = fmaf(2.0f, corr, uL[j8 * 8 + c]);
            rs[c] = f2bf(gelu_f(yv));
        }
        uint4 o;
        o.x = (unsigned)rs[0] | ((unsigned)rs[1] << 16);
        o.y = (unsigned)rs[2] | ((unsigned)rs[3] << 16);
        o.z = (unsigned)rs[4] | ((unsigned)rs[5] << 16);
        o.w = (unsigned)rs[6] | ((unsigned)rs[7] << 16);
        *(uint4*)(dst + j8 * 8) = o;
    }
}

// ---------------------------------------------------------------------------
// t16: yT (b, 256, 4096) bf16 -> yN (b, 4096, 256) bf16.  64x64 LDS tile.
// ---------------------------------------------------------------------------
__global__ __launch_bounds__(256) void t16_kernel(
    const unsigned short* __restrict__ src, unsigned short* __restrict__ dst)
{
    __shared__ unsigned short tl[64 * 66];
    const int tid = threadIdx.x;
    const int l0 = blockIdx.x * 64, h0 = blockIdx.y * 64, b = blockIdx.z;
    #pragma unroll
    for (int it = 0; it < 2; ++it) {
        int idx = it * 256 + tid; int r = idx >> 3, c8 = idx & 7;
        uint4 g = *(const uint4*)(src + ((size_t)(b * Hn + h0 + r)) * Ln + l0 + c8 * 8);
        unsigned short* p = &tl[r * 66 + c8 * 8];
        p[0] = g.x & 0xffff; p[1] = g.x >> 16;
        p[2] = g.y & 0xffff; p[3] = g.y >> 16;
        p[4] = g.z & 0xffff; p[5] = g.z >> 16;
        p[6] = g.w & 0xffff; p[7] = g.w >> 16;
    }
    __syncthreads();
    #pragma unroll
    for (int it = 0; it < 2; ++it) {
        int idx = it * 256 + tid; int hc = idx & 7, lr = idx >> 3;
        unsigned short e[8];
        #pragma unroll
        for (int j = 0; j < 8; ++j) e[j] = tl[(hc * 8 + j) * 66 + lr];
        uint4 o;
        o.x = (unsigned)e[0] | ((unsigned)e[1] << 16);
        o.y = (unsigned)e[2] | ((unsigned)e[3] << 16);
        o.z = (unsigned)e[4] | ((unsigned)e[5] << 16);
        o.w = (unsigned)e[6] | ((unsigned)e[7] << 16);
        *(uint4*)(dst + ((size_t)(b * Ln + l0 + lr)) * Hn + h0 + hc * 8) = o;
    }
}

// ---------------------------------------------------------------------------
// MFMA GEMM: C(M,256) = A(M,KDIM) @ W^T (+bias,+GLU,+resid).
// 128x64 tile, BK=64, 4 waves, mfma_f32_16x16x32_bf16.
// WRT: also writes transposed HTout (B,256,L) f32 via reused LDS tile.
// ---------------------------------------------------------------------------
template<int KDIM, bool GLU, bool ACVT, bool WRT>
__global__ __launch_bounds__(256) void mfma_gemm(
    const unsigned short* __restrict__ Abf,
    const float* __restrict__ Af,
    const float* __restrict__ W,
    const float* __restrict__ ba,
    const float* __restrict__ bg,
    const float* resid,              // aliases Hout (read-before-write, block-owned)
    float* Hout,                     // (M,256)
    float* HTout)                    // (B,256,L) f32
{
    constexpr int SM_MAIN = 128 * 72 * 2 + (GLU ? 2 : 1) * 64 * 72 * 2;
    constexpr int SM_TS = WRT ? (128 * 64 * 4) : 0;
    constexpr int SM = SM_MAIN > SM_TS ? SM_MAIN : SM_TS;
    __shared__ __align__(16) char smem[SM];
    unsigned short* As  = (unsigned short*)smem;
    unsigned short* Bs0 = As + 128 * 72;
    unsigned short* Bs1 = Bs0 + 64 * 72;   // GLU only
    float* ts = (float*)smem;              // reused after k-loop (WRT)

    const int tid = threadIdx.x;
    const int lane = tid & 63, w = tid >> 6;
    const int wm = w >> 1, wn = w & 1;
    const int lr = lane & 15, lq = lane >> 4;
    const int row0 = blockIdx.x * 128;
    const int n0 = blockIdx.y * 64;
    const int bb = row0 >> 12;
    const int l0 = row0 & (Ln - 1);

    f32x4 accA[4][2], accG[4][2];
    #pragma unroll
    for (int i = 0; i < 4; ++i)
        #pragma unroll
        for (int j = 0; j < 2; ++j) {
            accA[i][j] = (f32x4)0.0f;
            accG[i][j] = (f32x4)0.0f;
        }

    for (int kt = 0; kt < KDIM / 64; ++kt) {
        const int k0 = kt * 64;
        #pragma unroll
        for (int it = 0; it < 4; ++it) {
            int idx = it * 256 + tid; int m = idx >> 3, q = idx & 7;
            uint4 vv;
            if constexpr (ACVT) {
                const float* s = Af + (size_t)(row0 + m) * KDIM + k0 + q * 8;
                float4 g1 = *(const float4*)s;
                float4 g2 = *(const float4*)(s + 4);
                vv = pack8(g1, g2);
            } else {
                vv = *(const uint4*)(Abf + (size_t)(row0 + m) * KDIM + k0 + q * 8);
            }
            *(uint4*)(&As[m * 72 + q * 8]) = vv;
        }
        #pragma unroll
        for (int it = 0; it < 2; ++it) {
            int idx = it * 256 + tid; int p = idx >> 3, q = idx & 7;
            {
                const float* s = W + (size_t)(n0 + p) * KDIM + k0 + q * 8;
                float4 g1 = *(const float4*)s;
                float4 g2 = *(const float4*)(s + 4);
                *(uint4*)(&Bs0[p * 72 + q * 8]) = pack8(g1, g2);
            }
            if constexpr (GLU) {
                const float* s = W + (size_t)(256 + n0 + p) * KDIM + k0 + q * 8;
                float4 g1 = *(const float4*)s;
                float4 g2 = *(const float4*)(s + 4);
                *(uint4*)(&Bs1[p * 72 + q * 8]) = pack8(g1, g2);
            }
        }
        __syncthreads();
        #pragma unroll
        for (int kf = 0; kf < 2; ++kf) {
            bf16x8 av[4], bv[2], gv[2];
            #pragma unroll
            for (int mf = 0; mf < 4; ++mf)
                av[mf] = *(const bf16x8*)(&As[(wm * 64 + mf * 16 + lr) * 72 + (kf * 4 + lq) * 8]);
            #pragma unroll
            for (int nf = 0; nf < 2; ++nf) {
                bv[nf] = *(const bf16x8*)(&Bs0[(wn * 32 + nf * 16 + lr) * 72 + (kf * 4 + lq) * 8]);
                if constexpr (GLU)
                    gv[nf] = *(const bf16x8*)(&Bs1[(wn * 32 + nf * 16 + lr) * 72 + (kf * 4 + lq) * 8]);
            }
            #pragma unroll
            for (int mf = 0; mf < 4; ++mf)
                #pragma unroll
                for (int nf = 0; nf < 2; ++nf) {
                    accA[mf][nf] = __builtin_amdgcn_mfma_f32_16x16x32_bf16(av[mf], bv[nf], accA[mf][nf], 0, 0, 0);
                    if constexpr (GLU)
                        accG[mf][nf] = __builtin_amdgcn_mfma_f32_16x16x32_bf16(av[mf], gv[nf], accG[mf][nf], 0, 0, 0);
                }
        }
        __syncthreads();
    }

    // ---- epilogue ----
    int pc[2]; float bA[2], bG[2];
    #pragma unroll
    for (int nf = 0; nf < 2; ++nf) {
        pc[nf] = n0 + wn * 32 + nf * 16 + lr;
        bA[nf] = ba[pc[nf]];
        if constexpr (GLU) bG[nf] = bg[pc[nf]];
    }
    #pragma unroll
    for (int mf = 0; mf < 4; ++mf) {
        #pragma unroll
        for (int r = 0; r < 4; ++r) {
            int m_loc = wm * 64 + mf * 16 + lq * 4 + r;
            size_t rbase = (size_t)(row0 + m_loc) * Hn;
            #pragma unroll
            for (int nf = 0; nf < 2; ++nf) {
                float o;
                if constexpr (GLU) {
                    float aval = accA[mf][nf][r] + bA[nf];
                    float gval = accG[mf][nf][r] + bG[nf];
                    o = aval * sigmoid_f(gval) + resid[rbase + pc[nf]];
                } else {
                    o = accA[mf][nf][r] + bA[nf];
                }
                Hout[rbase + pc[nf]] = o;
                if constexpr (WRT)
                    ts[(wn * 32 + nf * 16 + lr) * 128 + m_loc] = o;
            }
        }
    }
    if constexpr (WRT) {
        __syncthreads();
        #pragma unroll
        for (int it = 0; it < 8; ++it) {
            int idx = it * 256 + tid;
            int nn = idx >> 5, m4 = (idx & 31) * 4;
            float4 o = *(const float4*)(&ts[nn * 128 + m4]);
            *(float4*)(HTout + (size_t)(bb * Hn + n0 + nn) * Ln + l0 + m4) = o;
        }
    }
}

extern "C" void kernel_launch(void* const* d_in, const int* in_sizes, int n_in,
                              void* d_out, int out_size, void* d_ws, size_t ws_size,
                              hipStream_t stream) {
    (void)in_sizes; (void)n_in; (void)out_size; (void)ws_size;
    const float* x          = (const float*)d_in[0];
    const float* enc_w      = (const float*)d_in[1];
    const float* enc_b      = (const float*)d_in[2];
    const float* log_dt     = (const float*)d_in[3];
    const float* log_A_real = (const float*)d_in[4];
    const float* A_imag     = (const float*)d_in[5];
    const float* C_re       = (const float*)d_in[6];
    const float* C_im       = (const float*)d_in[7];
    const float* D_skip     = (const float*)d_in[8];
    const float* out_w      = (const float*)d_in[9];
    const float* out_b      = (const float*)d_in[10];

    const size_t NE = (size_t)Bn * Hn * Ln;
    float* h  = (float*)d_out;                        // (B,L,H) residual stream
    float* hT = (float*)d_ws;                         // (B,H,L) f32
    unsigned short* yT = (unsigned short*)(hT + NE);  // (B,H,L) bf16
    unsigned short* yN = yT + NE;                     // (B,L,H) bf16

    const dim3 gb(256);

    // encoder: h,hT = x @ enc_w^T + enc_b
    mfma_gemm<DINn, false, true, true><<<dim3(256, 4), gb, 0, stream>>>(
        nullptr, x, enc_w, enc_b, nullptr, nullptr, h, hT);

    for (int i = 0; i < NLn; ++i) {
        s4_scan_kernel<<<dim3(Hn / 4, Bn), gb, 0, stream>>>(
            hT, yT,
            log_dt + (size_t)i * Hn,
            log_A_real + (size_t)i * Hn * N2n,
            A_imag + (size_t)i * Hn * N2n,
            C_re + (size_t)i * Hn * N2n,
            C_im + (size_t)i * Hn * N2n,
            D_skip + (size_t)i * Hn);
        t16_kernel<<<dim3(64, 4, 8), gb, 0, stream>>>(yT, yN);
        const float* wlay = out_w + (size_t)i * 2 * Hn * Hn;
        const float* bl = out_b + (size_t)i * 2 * Hn;
        if (i == NLn - 1) {
            mfma_gemm<Hn, true, false, false><<<dim3(256, 4), gb, 0, stream>>>(
                yN, nullptr, wlay, bl, bl + Hn, h, h, nullptr);
        } else {
            mfma_gemm<Hn, true, false, true><<<dim3(256, 4), gb, 0, stream>>>(
                yN, nullptr, wlay, bl, bl + Hn, h, h, hT);
        }
    }
}